// Round 7
// baseline (72.723 us; speedup 1.0000x reference)
//
#include <hip/hip_runtime.h>
#include <stdint.h>

#define NTOK 8192
#define NCOL 4096     // DIM == VOCAB
#define RANK 256
#define TPB  64       // tokens per block (4 waves x 16 tokens)
#define CPB  256      // cols per block (all waves share the B stream)

typedef __attribute__((ext_vector_type(8))) short bf16x8;
typedef __attribute__((ext_vector_type(4))) float f32x4;

__device__ __forceinline__ unsigned short f2bf(float f) {
    unsigned int u = __float_as_uint(f);
    u += 0x7fffu + ((u >> 16) & 1u);   // RNE
    return (unsigned short)(u >> 16);
}

// ---- combined pre-pass ----
// blocks [0, 1024): A fp32 [4096][256] -> bf16 row-major (Abf, 2 MiB, L2-resident)
// blocks [1024, 1536): B fp32 [256][4096] -> bf16 MFMA-fragment order
//   frag layout: flat uint4 index = (ct*8 + ks)*64 + lane, 8 bf16 each:
//     element j = B[ks*32 + (lane>>4)*8 + j][ct*16 + (lane&15)]
//   (same lane mapping works as A-operand: row-of-C = lane&15 = output col)
__global__ __launch_bounds__(256) void prep_kernel(
    const float* __restrict__ A, const float* __restrict__ B,
    unsigned short* __restrict__ Abf, unsigned short* __restrict__ Bfrag)
{
    if (blockIdx.x < 1024) {
        int i = blockIdx.x * 256 + threadIdx.x;
        float4 v = reinterpret_cast<const float4*>(A)[i];
        ushort4 o;
        o.x = f2bf(v.x); o.y = f2bf(v.y); o.z = f2bf(v.z); o.w = f2bf(v.w);
        reinterpret_cast<ushort4*>(Abf)[i] = o;
    } else {
        int gt = (blockIdx.x - 1024) * 256 + threadIdx.x;
        int ct = gt >> 9;
        int rem = gt & 511;
        int ks = rem >> 6;
        int ln = rem & 63;
        int col = ct * 16 + (ln & 15);
        int kb  = ks * 32 + ((ln >> 4) << 3);
        unsigned short pk[8];
        #pragma unroll
        for (int j = 0; j < 8; ++j)
            pk[j] = f2bf(B[(size_t)(kb + j) * NCOL + col]);
        uint4 o;
        o.x = (unsigned)pk[0] | ((unsigned)pk[1] << 16);
        o.y = (unsigned)pk[2] | ((unsigned)pk[3] << 16);
        o.z = (unsigned)pk[4] | ((unsigned)pk[5] << 16);
        o.w = (unsigned)pk[6] | ((unsigned)pk[7] << 16);
        reinterpret_cast<uint4*>(Bfrag)[gt] = o;
    }
}

// ---- main: fused gather + LoRA GEMM + W add + mask ----
// SWAPPED MFMA operands: D = Bfrag^T-role x Afrag-role, so each lane holds
// 4 CONSECUTIVE OUTPUT COLS of one token (token = lane&15, col=(lane>>4)*4+r)
// -> W-load and store become float4 (1 VMEM each per tile instead of 4+4).
__global__ __launch_bounds__(256, 4) void emb_lora_mfma(
    const int* __restrict__ x,
    const int* __restrict__ mask,
    const float* __restrict__ W,
    const unsigned short* __restrict__ Abf,
    const unsigned short* __restrict__ Bfrag,
    float* __restrict__ out)
{
    __shared__ int s_idx[TPB];
    __shared__ int s_msk[TPB];

    const int tid  = threadIdx.x;
    const int lane = tid & 63;
    const int wave = tid >> 6;        // token group: wave owns 16 tokens
    const int tok0 = blockIdx.x * TPB;
    const int col0 = blockIdx.y * CPB;

    if (tid < TPB) {
        s_idx[tid] = x[tok0 + tid];
        s_msk[tid] = mask[tok0 + tid];
    }
    __syncthreads();

    // this thread's token (B-operand col = lane&15 = C col index = token)
    const int trow  = wave * 16 + (lane & 15);
    const int tidx  = s_idx[trow];
    const int tmsk  = s_msk[trow];

    // A fragments (Y/B-operand): token = lane&15, k by (lane>>4, s)
    const unsigned short* ap = Abf + (size_t)tidx * RANK + ((lane >> 4) << 3);
    bf16x8 afrag[8];
    #pragma unroll
    for (int s = 0; s < 8; ++s)
        afrag[s] = *reinterpret_cast<const bf16x8*>(ap + s * 32);

    // per-thread W / out pointers: 4 consecutive cols at (lane>>4)*4
    const int colb = col0 + ((lane >> 4) << 2);
    const float4* wp4 = reinterpret_cast<const float4*>(
        W + (size_t)tidx * NCOL + colb);
    float4* op4 = reinterpret_cast<float4*>(
        out + (size_t)(tok0 + trow) * NCOL + colb);
    // per-tile stride in float4 units: 16 floats = 4 float4
    // tile t -> wp4[t*4], op4[t*4]

    // all 4 waves share these 16 col-tiles (B frags L1-resident after wave 0)
    const uint4* bcol = reinterpret_cast<const uint4*>(Bfrag)
                        + (size_t)(blockIdx.y * 16) * 512 + lane;

    // W prefetch ring, depth 4. Exec-masked `if` (NOT ternary — r3 lesson:
    // speculation doubled FETCH_SIZE).
    float4 wv[4];
    #pragma unroll
    for (int p = 0; p < 4; ++p) {
        float4 v = {0.f, 0.f, 0.f, 0.f};
        if (!tmsk) v = wp4[p * 4];
        wv[p] = v;
    }

#define TILE_BODY(T, SLOT, PF)                                           \
    {                                                                    \
        const int t_ = (T);                                              \
        uint4 bb[8];                                                     \
        _Pragma("unroll")                                                \
        for (int s = 0; s < 8; ++s)                                      \
            bb[s] = bcol[t_ * 512 + s * 64];                             \
        float4 wcur = wv[SLOT];                                          \
        if (PF) {                                                        \
            float4 v = {0.f, 0.f, 0.f, 0.f};                             \
            if (!tmsk) v = wp4[(t_ + 4) * 4];                            \
            wv[SLOT] = v;                                                \
        }                                                                \
        f32x4 acc0 = {0.f,0.f,0.f,0.f}, acc1 = {0.f,0.f,0.f,0.f};        \
        _Pragma("unroll")                                                \
        for (int s = 0; s < 4; ++s) {                                    \
            acc0 = __builtin_amdgcn_mfma_f32_16x16x32_bf16(              \
                __builtin_bit_cast(bf16x8, bb[s]), afrag[s], acc0, 0, 0, 0); \
            acc1 = __builtin_amdgcn_mfma_f32_16x16x32_bf16(              \
                __builtin_bit_cast(bf16x8, bb[s + 4]), afrag[s + 4], acc1, 0, 0, 0); \
        }                                                                \
        float4 o = {0.f, 0.f, 0.f, 0.f};                                 \
        if (!tmsk) {                                                     \
            o.x = acc0[0] + acc1[0] + wcur.x;                            \
            o.y = acc0[1] + acc1[1] + wcur.y;                            \
            o.z = acc0[2] + acc1[2] + wcur.z;                            \
            o.w = acc0[3] + acc1[3] + wcur.w;                            \
        }                                                                \
        op4[t_ * 4] = o;                                                 \
    }

    #pragma unroll 1
    for (int t0 = 0; t0 < 12; t0 += 4) {
        TILE_BODY(t0 + 0, 0, 1);
        TILE_BODY(t0 + 1, 1, 1);
        TILE_BODY(t0 + 2, 2, 1);
        TILE_BODY(t0 + 3, 3, 1);
    }
    // peeled tail: no prefetch (avoids OOB reads past the block's col range)
    TILE_BODY(12, 0, 0);
    TILE_BODY(13, 1, 0);
    TILE_BODY(14, 2, 0);
    TILE_BODY(15, 3, 0);
#undef TILE_BODY
}

extern "C" void kernel_launch(void* const* d_in, const int* in_sizes, int n_in,
                              void* d_out, int out_size, void* d_ws, size_t ws_size,
                              hipStream_t stream) {
    (void)in_sizes; (void)n_in; (void)out_size; (void)ws_size;

    const int*   x    = (const int*)d_in[0];
    const int*   mask = (const int*)d_in[1];
    const float* W    = (const float*)d_in[2];
    const float* A    = (const float*)d_in[3];
    const float* B    = (const float*)d_in[4];
    float*       out  = (float*)d_out;

    unsigned short* Abf   = (unsigned short*)d_ws;                       // 2 MiB
    unsigned short* Bfrag = (unsigned short*)((char*)d_ws + (2u << 20)); // 2 MiB

    prep_kernel<<<dim3(1536), dim3(256), 0, stream>>>(A, B, Abf, Bfrag);

    dim3 grid(NTOK / TPB, NCOL / CPB);   // (128, 16) = 2048 blocks
    emb_lora_mfma<<<grid, dim3(256), 0, stream>>>(x, mask, W, Abf, Bfrag, out);
}

// Round 8
// 55.448 us; speedup vs baseline: 1.3116x; 1.3116x over previous
//
#include <hip/hip_runtime.h>
#include <stdint.h>

#define NTOK 8192
#define NCOL 4096     // DIM == VOCAB
#define RANK 256
#define TPB  128      // tokens per block (4 waves x 32 tokens)
#define CPB  256      // cols per block

typedef __attribute__((ext_vector_type(8))) short bf16x8;
typedef __attribute__((ext_vector_type(4))) float f32x4;

__device__ __forceinline__ unsigned short f2bf(float f) {
    unsigned int u = __float_as_uint(f);
    u += 0x7fffu + ((u >> 16) & 1u);   // RNE
    return (unsigned short)(u >> 16);
}

// ---- combined pre-pass ----
// blocks [0, 1024): A fp32 [4096][256] -> bf16 row-major (Abf, 2 MiB, L2-resident)
// blocks [1024, 1536): B fp32 [256][4096] -> bf16 MFMA-B-fragment order
//   frag layout: flat uint4 index = (ct*8 + ks)*64 + lane, 8 bf16 each:
//     element j = B[ks*32 + (lane>>4)*8 + j][ct*16 + (lane&15)]
__global__ __launch_bounds__(256) void prep_kernel(
    const float* __restrict__ A, const float* __restrict__ B,
    unsigned short* __restrict__ Abf, unsigned short* __restrict__ Bfrag)
{
    if (blockIdx.x < 1024) {
        int i = blockIdx.x * 256 + threadIdx.x;
        float4 v = reinterpret_cast<const float4*>(A)[i];
        ushort4 o;
        o.x = f2bf(v.x); o.y = f2bf(v.y); o.z = f2bf(v.z); o.w = f2bf(v.w);
        reinterpret_cast<ushort4*>(Abf)[i] = o;
    } else {
        int gt = (blockIdx.x - 1024) * 256 + threadIdx.x;
        int ct = gt >> 9;
        int rem = gt & 511;
        int ks = rem >> 6;
        int ln = rem & 63;
        int col = ct * 16 + (ln & 15);
        int kb  = ks * 32 + ((ln >> 4) << 3);
        unsigned short pk[8];
        #pragma unroll
        for (int j = 0; j < 8; ++j)
            pk[j] = f2bf(B[(size_t)(kb + j) * NCOL + col]);
        uint4 o;
        o.x = (unsigned)pk[0] | ((unsigned)pk[1] << 16);
        o.y = (unsigned)pk[2] | ((unsigned)pk[3] << 16);
        o.z = (unsigned)pk[4] | ((unsigned)pk[5] << 16);
        o.w = (unsigned)pk[6] | ((unsigned)pk[7] << 16);
        reinterpret_cast<uint4*>(Bfrag)[gt] = o;
    }
}

// ---- main: fused gather + LoRA GEMM + W add + mask ----
// M-blocked: each wave owns 32 tokens (2 MFMA token-groups), so every
// B-fragment load feeds 2 chain-pairs -> B L1 traffic per output halves.
__global__ __launch_bounds__(256) void emb_lora_mfma(
    const int* __restrict__ x,
    const int* __restrict__ mask,
    const float* __restrict__ W,
    const unsigned short* __restrict__ Abf,
    const unsigned short* __restrict__ Bfrag,
    float* __restrict__ out)
{
    __shared__ int s_idx[TPB];
    __shared__ int s_msk[TPB];

    const int tid  = threadIdx.x;
    const int lane = tid & 63;
    const int wave = tid >> 6;        // wave owns tokens [wave*32, wave*32+32)
    const int tok0 = blockIdx.x * TPB;
    const int col0 = blockIdx.y * CPB;

    if (tid < TPB) {
        s_idx[tid] = x[tok0 + tid];
        s_msk[tid] = mask[tok0 + tid];
    }
    __syncthreads();

    // A fragments for both token groups (A-operand row = lane&15)
    const int a0row = s_idx[wave * 32 + (lane & 15)];
    const int a1row = s_idx[wave * 32 + 16 + (lane & 15)];
    const unsigned short* ap0 = Abf + (size_t)a0row * RANK + ((lane >> 4) << 3);
    const unsigned short* ap1 = Abf + (size_t)a1row * RANK + ((lane >> 4) << 3);
    bf16x8 aA[8], aB[8];
    #pragma unroll
    for (int s = 0; s < 8; ++s) {
        aA[s] = *reinterpret_cast<const bf16x8*>(ap0 + s * 32);
        aB[s] = *reinterpret_cast<const bf16x8*>(ap1 + s * 32);
    }

    // per-thread epilogue state: group g covers rows wave*32+g*16+(lane>>4)*4+r
    // 32-bit offsets (s-base + v-offset addressing keeps VGPR down)
    const int colb = col0 + (lane & 15);
    int msk0[4], msk1[4];
    unsigned woff0[4], woff1[4], ooff0[4], ooff1[4];
    #pragma unroll
    for (int r = 0; r < 4; ++r) {
        int row0 = wave * 32 + ((lane >> 4) << 2) + r;
        int row1 = row0 + 16;
        msk0[r] = s_msk[row0];
        msk1[r] = s_msk[row1];
        woff0[r] = (unsigned)s_idx[row0] * NCOL + colb;
        woff1[r] = (unsigned)s_idx[row1] * NCOL + colb;
        ooff0[r] = (unsigned)(tok0 + row0) * NCOL + colb;
        ooff1[r] = (unsigned)(tok0 + row1) * NCOL + colb;
    }

    // all 4 waves share these 16 col-tiles (B frags L1-resident after wave 0)
    const uint4* bcol = reinterpret_cast<const uint4*>(Bfrag)
                        + (size_t)(blockIdx.y * 16) * 512 + lane;

    // W prefetch rings, depth 2, exec-masked loads (explicit `if`, NOT
    // ternary — r3 lesson: speculation doubled FETCH_SIZE)
    float wv0[2][4], wv1[2][4];
    #pragma unroll
    for (int p = 0; p < 2; ++p) {
        #pragma unroll
        for (int r = 0; r < 4; ++r) {
            float v0 = 0.0f, v1 = 0.0f;
            if (!msk0[r]) v0 = W[woff0[r] + p * 16];
            if (!msk1[r]) v1 = W[woff1[r] + p * 16];
            wv0[p][r] = v0;
            wv1[p][r] = v1;
        }
    }

#define TILE_BODY(T, SLOT, PF)                                           \
    {                                                                    \
        const int t_ = (T);                                              \
        uint4 bb[8];                                                     \
        _Pragma("unroll")                                                \
        for (int s = 0; s < 8; ++s)                                      \
            bb[s] = bcol[t_ * 512 + s * 64];                             \
        float wc0[4], wc1[4];                                            \
        _Pragma("unroll")                                                \
        for (int r = 0; r < 4; ++r) { wc0[r] = wv0[SLOT][r]; wc1[r] = wv1[SLOT][r]; } \
        if (PF) {                                                        \
            _Pragma("unroll")                                            \
            for (int r = 0; r < 4; ++r) {                                \
                float v0 = 0.0f, v1 = 0.0f;                              \
                if (!msk0[r]) v0 = W[woff0[r] + (t_ + 2) * 16];          \
                if (!msk1[r]) v1 = W[woff1[r] + (t_ + 2) * 16];          \
                wv0[SLOT][r] = v0;                                       \
                wv1[SLOT][r] = v1;                                       \
            }                                                            \
        }                                                                \
        f32x4 acc00 = {0.f,0.f,0.f,0.f}, acc01 = {0.f,0.f,0.f,0.f};      \
        f32x4 acc10 = {0.f,0.f,0.f,0.f}, acc11 = {0.f,0.f,0.f,0.f};      \
        _Pragma("unroll")                                                \
        for (int s = 0; s < 4; ++s) {                                    \
            bf16x8 b0 = __builtin_bit_cast(bf16x8, bb[s]);               \
            bf16x8 b1 = __builtin_bit_cast(bf16x8, bb[s + 4]);           \
            acc00 = __builtin_amdgcn_mfma_f32_16x16x32_bf16(aA[s],     b0, acc00, 0, 0, 0); \
            acc01 = __builtin_amdgcn_mfma_f32_16x16x32_bf16(aA[s + 4], b1, acc01, 0, 0, 0); \
            acc10 = __builtin_amdgcn_mfma_f32_16x16x32_bf16(aB[s],     b0, acc10, 0, 0, 0); \
            acc11 = __builtin_amdgcn_mfma_f32_16x16x32_bf16(aB[s + 4], b1, acc11, 0, 0, 0); \
        }                                                                \
        _Pragma("unroll")                                                \
        for (int r = 0; r < 4; ++r) {                                    \
            float v0 = msk0[r] ? 0.0f : (acc00[r] + acc01[r] + wc0[r]);  \
            float v1 = msk1[r] ? 0.0f : (acc10[r] + acc11[r] + wc1[r]);  \
            out[ooff0[r] + t_ * 16] = v0;                                \
            out[ooff1[r] + t_ * 16] = v1;                                \
        }                                                                \
    }

    #pragma unroll 1
    for (int t0 = 0; t0 < 14; t0 += 2) {
        TILE_BODY(t0 + 0, 0, 1);
        TILE_BODY(t0 + 1, 1, 1);
    }
    // peeled tail: no prefetch (avoids OOB reads past the block's col range)
    TILE_BODY(14, 0, 0);
    TILE_BODY(15, 1, 0);
#undef TILE_BODY
}

extern "C" void kernel_launch(void* const* d_in, const int* in_sizes, int n_in,
                              void* d_out, int out_size, void* d_ws, size_t ws_size,
                              hipStream_t stream) {
    (void)in_sizes; (void)n_in; (void)out_size; (void)ws_size;

    const int*   x    = (const int*)d_in[0];
    const int*   mask = (const int*)d_in[1];
    const float* W    = (const float*)d_in[2];
    const float* A    = (const float*)d_in[3];
    const float* B    = (const float*)d_in[4];
    float*       out  = (float*)d_out;

    unsigned short* Abf   = (unsigned short*)d_ws;                       // 2 MiB
    unsigned short* Bfrag = (unsigned short*)((char*)d_ws + (2u << 20)); // 2 MiB

    prep_kernel<<<dim3(1536), dim3(256), 0, stream>>>(A, B, Abf, Bfrag);

    dim3 grid(NTOK / TPB, NCOL / CPB);   // (64, 16) = 1024 blocks
    emb_lora_mfma<<<grid, dim3(256), 0, stream>>>(x, mask, W, Abf, Bfrag, out);
}